// Round 7
// baseline (196.576 us; speedup 1.0000x reference)
//
#include <hip/hip_runtime.h>

#define NL 30

typedef float f2 __attribute__((ext_vector_type(2)));

// Pre-kernel: duplicate each scalar param into both lanes of an f2 so the
// main kernel s_loads ready-made 64-bit packed operands for v_pk_fma_f32.
// Layout per layer l (12 f2 slots = 96 B, s_load_dwordx8-friendly):
//   [0..4] w1 dup, [5] bias dup, [6..10] w2 dup, [11] pad.
__global__ void pack_params(const float* __restrict__ W1,
                            const float* __restrict__ b1,
                            const float* __restrict__ W2,
                            f2* __restrict__ pw) {
    int i = blockIdx.x * blockDim.x + threadIdx.x;
    if (i >= NL * 12) return;
    int l = i / 12, k = i % 12;
    float v = 0.0f;
    if (k < 5)       v = W1[l * 5 + k];
    else if (k == 5) v = b1[l];
    else if (k < 11) v = W2[l * 5 + (k - 6)];
    pw[i] = (f2){v, v};
}

// 2 rows/thread, packed f32 math, SGPR params, no LDS, full unroll.
// 32768 waves (128/CU) for latency hiding.
__global__ __launch_bounds__(256, 8) void drn_kernel(
    const float* __restrict__ x1, const float* __restrict__ x2,
    const f2* __restrict__ pw,
    float* __restrict__ o1, float* __restrict__ o2)
{
    long row = ((long)blockIdx.x * 256 + threadIdx.x) * 2;

    // x1: one f2 (8-B aligned). x2: 10 floats at 40-B-aligned offset -> 5 f2.
    f2 h1 = *(const f2*)(x1 + row);
    f2 h2[5];
    {
        const f2* p = (const f2*)(x2 + row * 5);
        f2 a0 = p[0], a1 = p[1], a2 = p[2], a3 = p[3], a4 = p[4];
        // a0={r0e0,r0e1} a1={r0e2,r0e3} a2={r0e4,r1e0} a3={r1e1,r1e2} a4={r1e3,r1e4}
        // Transpose to element-major pairs: h2[j] = {row0[j], row1[j]}.
        h2[0] = (f2){a0.x, a2.y};
        h2[1] = (f2){a0.y, a3.x};
        h2[2] = (f2){a1.x, a3.y};
        h2[3] = (f2){a1.y, a4.x};
        h2[4] = (f2){a2.x, a4.y};
    }

    const f2 zero = (f2){0.0f, 0.0f};

    #pragma unroll
    for (int l = 0; l < NL; ++l) {
        // Uniform indices on a __restrict__ readonly pointer -> s_load pairs.
        const f2* P = pw + l * 12;
        f2 w1d[5], w2d[5], bd;
        #pragma unroll
        for (int j = 0; j < 5; ++j) w1d[j] = P[j];
        bd = P[5];
        #pragma unroll
        for (int j = 0; j < 5; ++j) w2d[j] = P[6 + j];

        f2 s = h1 + bd;
        #pragma unroll
        for (int j = 0; j < 5; ++j)
            s = __builtin_elementwise_fma(__builtin_elementwise_max(h2[j], zero),
                                          w1d[j], s);
        h1 = s;
        f2 rh = __builtin_elementwise_max(s, zero);
        #pragma unroll
        for (int j = 0; j < 5; ++j)
            h2[j] = __builtin_elementwise_fma(rh, w2d[j], h2[j]);
    }

    // Store: o1 one f2; o2 transpose back to row-major, 5 f2.
    *(f2*)(o1 + row) = h1;
    {
        f2* p = (f2*)(o2 + row * 5);
        p[0] = (f2){h2[0].x, h2[1].x};
        p[1] = (f2){h2[2].x, h2[3].x};
        p[2] = (f2){h2[4].x, h2[0].y};
        p[3] = (f2){h2[1].y, h2[2].y};
        p[4] = (f2){h2[3].y, h2[4].y};
    }
}

extern "C" void kernel_launch(void* const* d_in, const int* in_sizes, int n_in,
                              void* d_out, int out_size, void* d_ws, size_t ws_size,
                              hipStream_t stream) {
    const float* x1 = (const float*)d_in[0];
    const float* x2 = (const float*)d_in[1];
    const float* W1 = (const float*)d_in[2];
    const float* b1 = (const float*)d_in[3];
    const float* W2 = (const float*)d_in[4];
    int nrows = in_sizes[0];            // 4,194,304
    float* o1 = (float*)d_out;          // [nrows]
    float* o2 = (float*)d_out + nrows;  // [nrows*5]
    f2* pw = (f2*)d_ws;                 // 30*12*8 = 2880 B scratch

    pack_params<<<2, 256, 0, stream>>>(W1, b1, W2, pw);

    int block = 256;
    int grid = nrows / (block * 2);     // 8192 blocks, 2 rows/thread
    drn_kernel<<<grid, block, 0, stream>>>(x1, x2, pw, o1, o2);
}